// Round 1
// baseline (213.467 us; speedup 1.0000x reference)
//
#include <hip/hip_runtime.h>

#define B_   4
#define LQ_  256
#define LK_  512
#define DIN_ 512
#define H_   256
#define DV_  512

// ---------------- projection: Y(rows,H) = X(rows,DIN) @ W(DIN,H) ----------------
__global__ __launch_bounds__(256) void proj_kernel(
    const float* __restrict__ X, const float* __restrict__ W,
    float* __restrict__ Y) {
  const int TR = 8;
  __shared__ float xs[TR][DIN_ + 1];
  const int rowBase = blockIdx.x * TR;
  const int h = threadIdx.x;  // 256 threads = H
  for (int idx = threadIdx.x; idx < TR * DIN_; idx += 256) {
    int r = idx >> 9;          // /512
    int d = idx & (DIN_ - 1);
    xs[r][d] = X[(size_t)(rowBase + r) * DIN_ + d];
  }
  __syncthreads();
  float acc[TR];
#pragma unroll
  for (int r = 0; r < TR; ++r) acc[r] = 0.f;
  for (int d = 0; d < DIN_; ++d) {
    float w = W[d * H_ + h];   // coalesced across threads
#pragma unroll
    for (int r = 0; r < TR; ++r) acc[r] = fmaf(xs[r][d], w, acc[r]);
  }
#pragma unroll
  for (int r = 0; r < TR; ++r) Y[(size_t)(rowBase + r) * H_ + h] = acc[r];
}

// ---------------- scores[b,i,j] = sum_h wv[h]*tanh(qp[b,i,h]+kp[b,j,h]) --------
__global__ __launch_bounds__(256) void scores_kernel(
    const float* __restrict__ qp, const float* __restrict__ kp,
    const float* __restrict__ wv, float* __restrict__ scores) {
  const int bi = blockIdx.x;        // b*LQ + i
  const int b = bi >> 8;            // LQ=256
  const int lane = threadIdx.x & 63;
  const int wave = threadIdx.x >> 6;  // 4 waves
  // each lane owns h = 4*lane .. 4*lane+3  (64*4 = 256 = H)
  const float4 qv  = *(const float4*)(qp + (size_t)bi * H_ + 4 * lane);
  const float4 wvv = *(const float4*)(wv + 4 * lane);
  const float* kpb = kp + (size_t)b * LK_ * H_;
  for (int j = wave; j < LK_; j += 4) {
    const float4 kv = *(const float4*)(kpb + (size_t)j * H_ + 4 * lane);
    float s = wvv.x * tanhf(qv.x + kv.x);
    s = fmaf(wvv.y, tanhf(qv.y + kv.y), s);
    s = fmaf(wvv.z, tanhf(qv.z + kv.z), s);
    s = fmaf(wvv.w, tanhf(qv.w + kv.w), s);
#pragma unroll
    for (int off = 32; off; off >>= 1) s += __shfl_xor(s, off);
    if (lane == 0) scores[(size_t)bi * LK_ + j] = s;
  }
}

// ---------------- masked softmax over LK + out = attn @ V ----------------------
__global__ __launch_bounds__(512) void softmax_av_kernel(
    const float* __restrict__ scores, const float* __restrict__ V,
    const int* __restrict__ valid_lens, float* __restrict__ out) {
  __shared__ float p[LK_];
  __shared__ float red[8];
  const int bi = blockIdx.x;
  const int b = bi >> 8;
  const int vl = valid_lens[b];
  const int t = threadIdx.x;        // 512 threads
  const int lane = t & 63, wave = t >> 6;

  float s = (t < vl) ? scores[(size_t)bi * LK_ + t] : -3.0e38f;
  // block max
  float m = s;
#pragma unroll
  for (int off = 32; off; off >>= 1) m = fmaxf(m, __shfl_xor(m, off));
  if (lane == 0) red[wave] = m;
  __syncthreads();
  float mx = red[0];
#pragma unroll
  for (int w = 1; w < 8; ++w) mx = fmaxf(mx, red[w]);
  __syncthreads();
  // block sum of exp
  float e = (t < vl) ? __expf(s - mx) : 0.f;
  float sum = e;
#pragma unroll
  for (int off = 32; off; off >>= 1) sum += __shfl_xor(sum, off);
  if (lane == 0) red[wave] = sum;
  __syncthreads();
  float tot = 0.f;
#pragma unroll
  for (int w = 0; w < 8; ++w) tot += red[w];
  p[t] = e / tot;
  __syncthreads();

  // out[bi, t] = sum_j p[j] * V[b, j, t]   (t indexes DV, coalesced)
  const float* Vb = V + (size_t)b * LK_ * DV_;
  float acc = 0.f;
  for (int j = 0; j < vl; ++j) acc = fmaf(p[j], Vb[(size_t)j * DV_ + t], acc);
  out[(size_t)bi * DV_ + t] = acc;
}

extern "C" void kernel_launch(void* const* d_in, const int* in_sizes, int n_in,
                              void* d_out, int out_size, void* d_ws, size_t ws_size,
                              hipStream_t stream) {
  const float* queries    = (const float*)d_in[0];
  const float* keys       = (const float*)d_in[1];
  const float* values     = (const float*)d_in[2];
  const int*   valid_lens = (const int*)d_in[3];
  const float* Wq         = (const float*)d_in[4];
  const float* Wk         = (const float*)d_in[5];
  const float* wv         = (const float*)d_in[6];
  float* out = (float*)d_out;

  char* ws = (char*)d_ws;
  float* qp = (float*)ws;                          // B*LQ*H   = 1 MB
  float* kp = (float*)(ws + (size_t)(1 << 20));    // B*LK*H   = 2 MB
  float* sc = (float*)(ws + (size_t)(3 << 20));    // B*LQ*LK  = 2 MB

  proj_kernel<<<(B_ * LQ_) / 8, 256, 0, stream>>>(queries, Wq, qp);
  proj_kernel<<<(B_ * LK_) / 8, 256, 0, stream>>>(keys,    Wk, kp);
  scores_kernel<<<B_ * LQ_, 256, 0, stream>>>(qp, kp, wv, sc);
  softmax_av_kernel<<<B_ * LQ_, 512, 0, stream>>>(sc, values, valid_lens, out);
}

// Round 2
// 177.236 us; speedup vs baseline: 1.2044x; 1.2044x over previous
//
#include <hip/hip_runtime.h>

#define B_   4
#define LQ_  256
#define LK_  512
#define DIN_ 512
#define H_   256
#define DV_  512

// tanh(x) = 1 - 2/(exp(2x)+1), via native v_exp_f32 + v_rcp_f32.
// Rel err ~1e-6; saturates correctly at +/-1 for |x| large.
__device__ __forceinline__ float fast_tanh(float x) {
  float e = exp2f(x * 2.885390081777927f);   // exp(2x) = 2^(2x*log2 e)
  float r = __builtin_amdgcn_rcpf(e + 1.0f); // v_rcp_f32
  return fmaf(-2.0f, r, 1.0f);
}

// ---------------- projection: Y(rows,H) = X(rows,DIN) @ W(DIN,H) ----------------
__global__ __launch_bounds__(256) void proj_kernel(
    const float* __restrict__ X, const float* __restrict__ W,
    float* __restrict__ Y) {
  const int TR = 8;
  __shared__ float xs[TR][DIN_ + 1];
  const int rowBase = blockIdx.x * TR;
  const int h = threadIdx.x;  // 256 threads = H
  for (int idx = threadIdx.x; idx < TR * DIN_; idx += 256) {
    int r = idx >> 9;          // /512
    int d = idx & (DIN_ - 1);
    xs[r][d] = X[(size_t)(rowBase + r) * DIN_ + d];
  }
  __syncthreads();
  float acc[TR];
#pragma unroll
  for (int r = 0; r < TR; ++r) acc[r] = 0.f;
  for (int d = 0; d < DIN_; ++d) {
    float w = W[d * H_ + h];   // coalesced across threads
#pragma unroll
    for (int r = 0; r < TR; ++r) acc[r] = fmaf(xs[r][d], w, acc[r]);
  }
#pragma unroll
  for (int r = 0; r < TR; ++r) Y[(size_t)(rowBase + r) * H_ + h] = acc[r];
}

// ---------------- scores[b,i,j] = sum_h wv[h]*tanh(qp[b,i,h]+kp[b,j,h]) --------
__global__ __launch_bounds__(256) void scores_kernel(
    const float* __restrict__ qp, const float* __restrict__ kp,
    const float* __restrict__ wv, float* __restrict__ scores) {
  const int bi = blockIdx.x;        // b*LQ + i
  const int b = bi >> 8;            // LQ=256
  const int lane = threadIdx.x & 63;
  const int wave = threadIdx.x >> 6;  // 4 waves
  // each lane owns h = 4*lane .. 4*lane+3  (64*4 = 256 = H)
  const float4 qv  = *(const float4*)(qp + (size_t)bi * H_ + 4 * lane);
  const float4 wvv = *(const float4*)(wv + 4 * lane);
  const float* kpb = kp + (size_t)b * LK_ * H_;
  for (int j = wave; j < LK_; j += 4) {
    const float4 kv = *(const float4*)(kpb + (size_t)j * H_ + 4 * lane);
    float s = wvv.x * fast_tanh(qv.x + kv.x);
    s = fmaf(wvv.y, fast_tanh(qv.y + kv.y), s);
    s = fmaf(wvv.z, fast_tanh(qv.z + kv.z), s);
    s = fmaf(wvv.w, fast_tanh(qv.w + kv.w), s);
#pragma unroll
    for (int off = 32; off; off >>= 1) s += __shfl_xor(s, off);
    if (lane == 0) scores[(size_t)bi * LK_ + j] = s;
  }
}

// ---------------- masked softmax over LK + out = attn @ V ----------------------
__global__ __launch_bounds__(512) void softmax_av_kernel(
    const float* __restrict__ scores, const float* __restrict__ V,
    const int* __restrict__ valid_lens, float* __restrict__ out) {
  __shared__ float p[LK_];
  __shared__ float red[8];
  const int bi = blockIdx.x;
  const int b = bi >> 8;
  const int vl = valid_lens[b];
  const int t = threadIdx.x;        // 512 threads
  const int lane = t & 63, wave = t >> 6;

  float s = (t < vl) ? scores[(size_t)bi * LK_ + t] : -3.0e38f;
  // block max
  float m = s;
#pragma unroll
  for (int off = 32; off; off >>= 1) m = fmaxf(m, __shfl_xor(m, off));
  if (lane == 0) red[wave] = m;
  __syncthreads();
  float mx = red[0];
#pragma unroll
  for (int w = 1; w < 8; ++w) mx = fmaxf(mx, red[w]);
  __syncthreads();
  // block sum of exp
  float e = (t < vl) ? __expf(s - mx) : 0.f;
  float sum = e;
#pragma unroll
  for (int off = 32; off; off >>= 1) sum += __shfl_xor(sum, off);
  if (lane == 0) red[wave] = sum;
  __syncthreads();
  float tot = 0.f;
#pragma unroll
  for (int w = 0; w < 8; ++w) tot += red[w];
  p[t] = e / tot;
  __syncthreads();

  // out[bi, t] = sum_j p[j] * V[b, j, t]   (t indexes DV, coalesced)
  const float* Vb = V + (size_t)b * LK_ * DV_;
  float acc = 0.f;
  for (int j = 0; j < vl; ++j) acc = fmaf(p[j], Vb[(size_t)j * DV_ + t], acc);
  out[(size_t)bi * DV_ + t] = acc;
}

extern "C" void kernel_launch(void* const* d_in, const int* in_sizes, int n_in,
                              void* d_out, int out_size, void* d_ws, size_t ws_size,
                              hipStream_t stream) {
  const float* queries    = (const float*)d_in[0];
  const float* keys       = (const float*)d_in[1];
  const float* values     = (const float*)d_in[2];
  const int*   valid_lens = (const int*)d_in[3];
  const float* Wq         = (const float*)d_in[4];
  const float* Wk         = (const float*)d_in[5];
  const float* wv         = (const float*)d_in[6];
  float* out = (float*)d_out;

  char* ws = (char*)d_ws;
  float* qp = (float*)ws;                          // B*LQ*H   = 1 MB
  float* kp = (float*)(ws + (size_t)(1 << 20));    // B*LK*H   = 2 MB
  float* sc = (float*)(ws + (size_t)(3 << 20));    // B*LQ*LK  = 2 MB

  proj_kernel<<<(B_ * LQ_) / 8, 256, 0, stream>>>(queries, Wq, qp);
  proj_kernel<<<(B_ * LK_) / 8, 256, 0, stream>>>(keys,    Wk, kp);
  scores_kernel<<<B_ * LQ_, 256, 0, stream>>>(qp, kp, wv, sc);
  softmax_av_kernel<<<B_ * LQ_, 512, 0, stream>>>(sc, values, valid_lens, out);
}

// Round 3
// 151.175 us; speedup vs baseline: 1.4121x; 1.1724x over previous
//
#include <hip/hip_runtime.h>

#define B_   4
#define LQ_  256
#define LK_  512
#define DIN_ 512
#define H_   256
#define DV_  512

// 2*log2(e): fold into projection outputs so tanh(x)=1-2/(exp2(x')+1), x'=2x*log2e
#define TANH_SCALE 2.885390081777927f

// =====================================================================
// Kernel A: both projections, transposed + pre-scaled outputs.
//   qpT[b][h][i] = TANH_SCALE * sum_d Q[b,i,d] Wq[d,h]   (B,H,LQ)
//   kpT[b][h][j] = TANH_SCALE * sum_d K[b,j,d] Wk[d,h]   (B,H,LK)
// thread = one h column; 8 rows per block; x values are wave-uniform -> s_load.
// Block 0 wave 0 also computes Wsum = sum_h wv[h].
// =====================================================================
__global__ __launch_bounds__(256) void proj_kernel(
    const float* __restrict__ Q, const float* __restrict__ K,
    const float* __restrict__ Wq, const float* __restrict__ Wk,
    const float* __restrict__ wv,
    float* __restrict__ qpT, float* __restrict__ kpT, float* __restrict__ wsum) {
  const int blk = blockIdx.x;               // 0..383
  const bool isQ = blk < (B_ * LQ_ / 8);    // first 128 blocks: queries
  const float* __restrict__ X = isQ ? Q : K;
  const float* __restrict__ W = isQ ? Wq : Wk;
  float* __restrict__ YT = isQ ? qpT : kpT;
  const int L = isQ ? LQ_ : LK_;
  const int rowBase = (isQ ? blk : blk - (B_ * LQ_ / 8)) * 8;  // flat row (b*L + r)
  const int b = rowBase / L;
  const int rloc = rowBase - b * L;
  const int h = threadIdx.x;

  const float* __restrict__ xrow = X + (size_t)rowBase * DIN_;  // uniform base
  float acc[8] = {0.f, 0.f, 0.f, 0.f, 0.f, 0.f, 0.f, 0.f};
#pragma unroll 4
  for (int d = 0; d < DIN_; ++d) {
    const float w = W[d * H_ + h];          // coalesced vector load
#pragma unroll
    for (int r = 0; r < 8; ++r)             // xrow[...] wave-uniform -> s_load
      acc[r] = fmaf(xrow[r * DIN_ + d], w, acc[r]);
  }
  float* dst = YT + ((size_t)b * H_ + h) * L + rloc;  // 8 consecutive floats/thread
  float4 lo = {acc[0] * TANH_SCALE, acc[1] * TANH_SCALE, acc[2] * TANH_SCALE, acc[3] * TANH_SCALE};
  float4 hi = {acc[4] * TANH_SCALE, acc[5] * TANH_SCALE, acc[6] * TANH_SCALE, acc[7] * TANH_SCALE};
  *(float4*)dst = lo;
  *(float4*)(dst + 4) = hi;

  if (blk == 0 && threadIdx.x < 64) {
    const int l = threadIdx.x;
    float s = wv[l] + wv[l + 64] + wv[l + 128] + wv[l + 192];
#pragma unroll
    for (int off = 32; off; off >>= 1) s += __shfl_xor(s, off);
    if (l == 0) *wsum = s;
  }
}

// =====================================================================
// Kernel B: scores[b,i,j] = Wsum - 2 * sum_h wv[h] * rcp(1 + exp2(qpT+kpT))
// lane = j (coalesced kT loads), TI=4 i's per thread, h-loop in registers.
// No cross-lane ops, no LDS. q4/wv loads wave-uniform -> scalar.
// grid 512 blocks x 256 thr: b = blk>>7, it = (blk>>1)&63, jt = blk&1
// =====================================================================
__global__ __launch_bounds__(256) void scores_kernel(
    const float* __restrict__ qpT, const float* __restrict__ kpT,
    const float* __restrict__ wv, const float* __restrict__ wsum,
    float* __restrict__ scores) {
  const int b  = blockIdx.x >> 7;
  const int i0 = ((blockIdx.x >> 1) & 63) * 4;
  const int j  = (blockIdx.x & 1) * 256 + threadIdx.x;

  const float* __restrict__ kcol = kpT + (size_t)b * H_ * LK_ + j;
  const float* __restrict__ qcol = qpT + (size_t)b * H_ * LQ_ + i0;
  const float Wsum = *wsum;

  float a0 = 0.f, a1 = 0.f, a2 = 0.f, a3 = 0.f;
#pragma unroll 4
  for (int h = 0; h < H_; ++h) {
    const float kv = kcol[(size_t)h * LK_];                    // coalesced
    const float4 q4 = *(const float4*)(qcol + (size_t)h * LQ_); // uniform
    const float wvh = wv[h];                                    // uniform
    a0 = fmaf(wvh, __builtin_amdgcn_rcpf(exp2f(q4.x + kv) + 1.f), a0);
    a1 = fmaf(wvh, __builtin_amdgcn_rcpf(exp2f(q4.y + kv) + 1.f), a1);
    a2 = fmaf(wvh, __builtin_amdgcn_rcpf(exp2f(q4.z + kv) + 1.f), a2);
    a3 = fmaf(wvh, __builtin_amdgcn_rcpf(exp2f(q4.w + kv) + 1.f), a3);
  }
  const size_t o = ((size_t)(b * LQ_ + i0)) * LK_ + j;
  scores[o]            = fmaf(-2.f, a0, Wsum);
  scores[o + LK_]      = fmaf(-2.f, a1, Wsum);
  scores[o + 2 * LK_]  = fmaf(-2.f, a2, Wsum);
  scores[o + 3 * LK_]  = fmaf(-2.f, a3, Wsum);
}

// =====================================================================
// Kernel C: masked softmax + AV for TI=4 query rows per block.
// 512 threads: t = j for softmax phase, t = v-column for AV phase.
// p stored as float4[LK] in LDS -> AV inner: 1 load + 1 broadcast b128 + 4 fma.
// =====================================================================
__global__ __launch_bounds__(512) void softmax_av_kernel(
    const float* __restrict__ scores, const float* __restrict__ V,
    const int* __restrict__ valid_lens, float* __restrict__ out) {
  __shared__ float4 p4s[LK_];     // 8 KB
  __shared__ float redm[8][4];
  __shared__ float reds[8][4];

  const int blk = blockIdx.x;     // 256 blocks
  const int b = blk >> 6;
  const int i0 = (blk & 63) * 4;
  const int vl = valid_lens[b];
  const int t = threadIdx.x;
  const int lane = t & 63, wave = t >> 6;

  const float* __restrict__ srow = scores + ((size_t)(b * LQ_ + i0)) * LK_;
  const bool valid = t < vl;
  float s[4], m[4];
#pragma unroll
  for (int ii = 0; ii < 4; ++ii) {
    s[ii] = valid ? srow[ii * LK_ + t] : -3.0e38f;
    m[ii] = s[ii];
  }
#pragma unroll
  for (int off = 32; off; off >>= 1) {
#pragma unroll
    for (int ii = 0; ii < 4; ++ii) m[ii] = fmaxf(m[ii], __shfl_xor(m[ii], off));
  }
  if (lane == 0) {
#pragma unroll
    for (int ii = 0; ii < 4; ++ii) redm[wave][ii] = m[ii];
  }
  __syncthreads();
  float mx[4], e[4], sum[4];
#pragma unroll
  for (int ii = 0; ii < 4; ++ii) {
    mx[ii] = redm[0][ii];
#pragma unroll
    for (int w = 1; w < 8; ++w) mx[ii] = fmaxf(mx[ii], redm[w][ii]);
    e[ii] = valid ? __expf(s[ii] - mx[ii]) : 0.f;
    sum[ii] = e[ii];
  }
#pragma unroll
  for (int off = 32; off; off >>= 1) {
#pragma unroll
    for (int ii = 0; ii < 4; ++ii) sum[ii] += __shfl_xor(sum[ii], off);
  }
  if (lane == 0) {
#pragma unroll
    for (int ii = 0; ii < 4; ++ii) reds[wave][ii] = sum[ii];
  }
  __syncthreads();
  float4 pv;
  {
    float tot[4];
#pragma unroll
    for (int ii = 0; ii < 4; ++ii) {
      tot[ii] = reds[0][ii];
#pragma unroll
      for (int w = 1; w < 8; ++w) tot[ii] += reds[w][ii];
    }
    pv.x = e[0] * __builtin_amdgcn_rcpf(tot[0]);
    pv.y = e[1] * __builtin_amdgcn_rcpf(tot[1]);
    pv.z = e[2] * __builtin_amdgcn_rcpf(tot[2]);
    pv.w = e[3] * __builtin_amdgcn_rcpf(tot[3]);
  }
  p4s[t] = pv;
  __syncthreads();

  // AV: t = v-column
  const float* __restrict__ Vb = V + (size_t)b * LK_ * DV_ + t;
  float a[4] = {0.f, 0.f, 0.f, 0.f};
#pragma unroll 2
  for (int j = 0; j < vl; ++j) {
    const float v = Vb[(size_t)j * DV_];
    const float4 pp = p4s[j];    // uniform broadcast
    a[0] = fmaf(pp.x, v, a[0]);
    a[1] = fmaf(pp.y, v, a[1]);
    a[2] = fmaf(pp.z, v, a[2]);
    a[3] = fmaf(pp.w, v, a[3]);
  }
#pragma unroll
  for (int ii = 0; ii < 4; ++ii)
    out[((size_t)(b * LQ_ + i0 + ii)) * DV_ + t] = a[ii];
}

extern "C" void kernel_launch(void* const* d_in, const int* in_sizes, int n_in,
                              void* d_out, int out_size, void* d_ws, size_t ws_size,
                              hipStream_t stream) {
  const float* queries    = (const float*)d_in[0];
  const float* keys       = (const float*)d_in[1];
  const float* values     = (const float*)d_in[2];
  const int*   valid_lens = (const int*)d_in[3];
  const float* Wq         = (const float*)d_in[4];
  const float* Wk         = (const float*)d_in[5];
  const float* wv         = (const float*)d_in[6];
  float* out = (float*)d_out;

  char* ws = (char*)d_ws;
  float* qpT  = (float*)ws;                          // B*H*LQ = 1 MB
  float* kpT  = (float*)(ws + (size_t)(1 << 20));    // B*H*LK = 2 MB
  float* sc   = (float*)(ws + (size_t)(3 << 20));    // B*LQ*LK = 2 MB
  float* wsum = (float*)(ws + (size_t)(5 << 20));    // 4 B

  proj_kernel<<<(B_ * LQ_ + B_ * LK_) / 8, 256, 0, stream>>>(
      queries, keys, Wq, Wk, wv, qpT, kpT, wsum);
  scores_kernel<<<B_ * (LQ_ / 4) * (LK_ / 256), 256, 0, stream>>>(
      qpT, kpT, wv, wsum, sc);
  softmax_av_kernel<<<B_ * (LQ_ / 4), 512, 0, stream>>>(
      sc, values, valid_lens, out);
}

// Round 4
// 90.802 us; speedup vs baseline: 2.3509x; 1.6649x over previous
//
#include <hip/hip_runtime.h>

#define B_   4
#define LQ_  256
#define LK_  512
#define DIN_ 512
#define H_   256
#define DV_  512

// 2*log2(e): folded into projections so tanh(x) = 1 - 2*rcp(exp2(x')+1), x'=2x*log2e
#define TANH_SCALE 2.885390081777927f

// =====================================================================
// Kernel A: projections. 256 thr, 8 rows/block.
//  blocks [0,128):   qp[b,i,h]  = TANH_SCALE * Q@Wq   (row-major: scalar-read later)
//  blocks [128,384): kpT[b,h,j] = TANH_SCALE * K@Wk   (transposed: vector-read later)
//  K-blocks with all rows >= valid_len exit immediately (never read downstream).
//  Thread micro-tile: 2 rows x 4 cols. X staged in LDS (16 KB).
// =====================================================================
__global__ __launch_bounds__(256) void proj_kernel(
    const float* __restrict__ Q, const float* __restrict__ K,
    const float* __restrict__ Wq, const float* __restrict__ Wk,
    const float* __restrict__ wv, const int* __restrict__ valid_lens,
    float* __restrict__ qp, float* __restrict__ kpT, float* __restrict__ wsum) {
  __shared__ float xs[8][DIN_];
  const int blk = blockIdx.x;
  const bool isQ = blk < (B_ * LQ_ / 8);
  const int flat = (isQ ? blk : blk - B_ * LQ_ / 8) * 8;   // flat row in (B*L)
  const int b    = isQ ? (flat >> 8) : (flat >> 9);
  const int rloc = isQ ? (flat & (LQ_ - 1)) : (flat & (LK_ - 1));

  if (!isQ && rloc >= valid_lens[b]) return;   // whole block masked out

  const float* __restrict__ X = (isQ ? Q : K) + (size_t)flat * DIN_;
  const float* __restrict__ W = isQ ? Wq : Wk;
  const int t = threadIdx.x;

  // stage 8 rows of X (coalesced float4)
#pragma unroll
  for (int u = 0; u < 4; ++u) {
    const int f = t + 256 * u;            // float4 index 0..1023
    const int r = f >> 7, c4 = (f & 127) << 2;
    *(float4*)&xs[r][c4] = *(const float4*)&X[(size_t)r * DIN_ + c4];
  }
  __syncthreads();

  const int tc = t & 63;        // col group: h = 4*tc
  const int tr = t >> 6;        // row pair: rows 2tr, 2tr+1
  float accA[4] = {0.f, 0.f, 0.f, 0.f};
  float accB[4] = {0.f, 0.f, 0.f, 0.f};
  for (int d = 0; d < DIN_; d += 4) {
    const float4 xa = *(const float4*)&xs[2 * tr][d];
    const float4 xb = *(const float4*)&xs[2 * tr + 1][d];
    const float xaa[4] = {xa.x, xa.y, xa.z, xa.w};
    const float xbb[4] = {xb.x, xb.y, xb.z, xb.w};
#pragma unroll
    for (int u = 0; u < 4; ++u) {
      const float4 w = *(const float4*)&W[(size_t)(d + u) * H_ + 4 * tc];
      accA[0] = fmaf(xaa[u], w.x, accA[0]); accA[1] = fmaf(xaa[u], w.y, accA[1]);
      accA[2] = fmaf(xaa[u], w.z, accA[2]); accA[3] = fmaf(xaa[u], w.w, accA[3]);
      accB[0] = fmaf(xbb[u], w.x, accB[0]); accB[1] = fmaf(xbb[u], w.y, accB[1]);
      accB[2] = fmaf(xbb[u], w.z, accB[2]); accB[3] = fmaf(xbb[u], w.w, accB[3]);
    }
  }

  if (isQ) {
    // row-major store, coalesced float4 along h
    float4 lo = {accA[0] * TANH_SCALE, accA[1] * TANH_SCALE, accA[2] * TANH_SCALE, accA[3] * TANH_SCALE};
    float4 hi = {accB[0] * TANH_SCALE, accB[1] * TANH_SCALE, accB[2] * TANH_SCALE, accB[3] * TANH_SCALE};
    *(float4*)&qp[(size_t)(flat + 2 * tr) * H_ + 4 * tc] = lo;
    *(float4*)&qp[(size_t)(flat + 2 * tr + 1) * H_ + 4 * tc] = hi;
  } else {
    // transposed store kpT[b,h,j]: 2 consecutive j per h -> float2
#pragma unroll
    for (int c = 0; c < 4; ++c) {
      float2 v = {accA[c] * TANH_SCALE, accB[c] * TANH_SCALE};
      *(float2*)&kpT[((size_t)b * H_ + 4 * tc + c) * LK_ + rloc + 2 * tr] = v;
    }
  }

  if (blk == 0 && t < 64) {
    float s = wv[t] + wv[t + 64] + wv[t + 128] + wv[t + 192];
#pragma unroll
    for (int off = 32; off; off >>= 1) s += __shfl_xor(s, off);
    if (t == 0) *wsum = s;
  }
}

// =====================================================================
// Kernel B: scores[b,i,j] = Wsum - 2*sum_h wv[h]*rcp(1+exp2(qp+kpT))
// TI=2 rows/block, j-chunk=256 -> 1024 blocks (4/CU). lane = j, h-loop in regs,
// zero cross-lane ops. Block-skip + wave-skip for j >= valid_len.
// =====================================================================
__global__ __launch_bounds__(256) void scores_kernel(
    const float* __restrict__ qp, const float* __restrict__ kpT,
    const float* __restrict__ wv, const float* __restrict__ wsum,
    const int* __restrict__ valid_lens, float* __restrict__ scores) {
  const int blk = blockIdx.x;
  const int b  = blk >> 8;
  const int r  = blk & 255;
  const int i0 = (r >> 1) * 2;
  const int jh = (r & 1) * 256;
  const int vl = valid_lens[b];
  if (jh >= vl) return;                           // whole block masked
  const int t = threadIdx.x;
  if (jh + ((t >> 6) << 6) >= vl) return;         // wave-uniform skip (64-gran)
  const int j = jh + t;

  const float* __restrict__ kcol = kpT + (size_t)b * H_ * LK_ + j;
  const float* __restrict__ q0 = qp + (size_t)(b * LQ_ + i0) * H_;
  const float* __restrict__ q1 = q0 + H_;
  const float Wsum = *wsum;

  float a0 = 0.f, a1 = 0.f;
#pragma unroll 4
  for (int h = 0; h < H_; ++h) {
    const float kv  = kcol[(size_t)h * LK_];      // coalesced vector load
    const float wvh = wv[h];                      // uniform scalar
    a0 = fmaf(wvh, __builtin_amdgcn_rcpf(exp2f(q0[h] + kv) + 1.f), a0);
    a1 = fmaf(wvh, __builtin_amdgcn_rcpf(exp2f(q1[h] + kv) + 1.f), a1);
  }
  const size_t o = (size_t)(b * LQ_ + i0) * LK_ + j;
  scores[o]       = fmaf(-2.f, a0, Wsum);
  scores[o + LK_] = fmaf(-2.f, a1, Wsum);
}

// =====================================================================
// Kernel C: masked softmax + AV, TI=4 rows/block, 512 thr.
// AV: thread = v-column, j-loop unrolled x8 (8 loads in flight).
// =====================================================================
__global__ __launch_bounds__(512) void softmax_av_kernel(
    const float* __restrict__ scores, const float* __restrict__ V,
    const int* __restrict__ valid_lens, float* __restrict__ out) {
  __shared__ float4 p4s[LK_];
  __shared__ float redm[8][4];
  __shared__ float reds[8][4];

  const int blk = blockIdx.x;
  const int b = blk >> 6;
  const int i0 = (blk & 63) * 4;
  const int vl = valid_lens[b];
  const int t = threadIdx.x;
  const int lane = t & 63, wave = t >> 6;

  const float* __restrict__ srow = scores + (size_t)(b * LQ_ + i0) * LK_;
  const bool valid = t < vl;
  float s[4], m[4];
#pragma unroll
  for (int ii = 0; ii < 4; ++ii) {
    s[ii] = valid ? srow[ii * LK_ + t] : -3.0e38f;
    m[ii] = s[ii];
  }
#pragma unroll
  for (int off = 32; off; off >>= 1)
#pragma unroll
    for (int ii = 0; ii < 4; ++ii) m[ii] = fmaxf(m[ii], __shfl_xor(m[ii], off));
  if (lane == 0)
#pragma unroll
    for (int ii = 0; ii < 4; ++ii) redm[wave][ii] = m[ii];
  __syncthreads();
  float e[4], sum[4];
#pragma unroll
  for (int ii = 0; ii < 4; ++ii) {
    float mx = redm[0][ii];
#pragma unroll
    for (int w = 1; w < 8; ++w) mx = fmaxf(mx, redm[w][ii]);
    e[ii] = valid ? __expf(s[ii] - mx) : 0.f;
    sum[ii] = e[ii];
  }
#pragma unroll
  for (int off = 32; off; off >>= 1)
#pragma unroll
    for (int ii = 0; ii < 4; ++ii) sum[ii] += __shfl_xor(sum[ii], off);
  if (lane == 0)
#pragma unroll
    for (int ii = 0; ii < 4; ++ii) reds[wave][ii] = sum[ii];
  __syncthreads();
  {
    float4 pv;
    float tot[4];
#pragma unroll
    for (int ii = 0; ii < 4; ++ii) {
      tot[ii] = reds[0][ii];
#pragma unroll
      for (int w = 1; w < 8; ++w) tot[ii] += reds[w][ii];
    }
    pv.x = e[0] * __builtin_amdgcn_rcpf(tot[0]);
    pv.y = e[1] * __builtin_amdgcn_rcpf(tot[1]);
    pv.z = e[2] * __builtin_amdgcn_rcpf(tot[2]);
    pv.w = e[3] * __builtin_amdgcn_rcpf(tot[3]);
    p4s[t] = pv;
  }
  __syncthreads();

  const float* __restrict__ Vb = V + (size_t)b * LK_ * DV_ + t;
  float a[4] = {0.f, 0.f, 0.f, 0.f};
  int j = 0;
  const int jv = vl & ~7;
  for (; j < jv; j += 8) {
    float v[8];
#pragma unroll
    for (int u = 0; u < 8; ++u) v[u] = Vb[(size_t)(j + u) * DV_];
#pragma unroll
    for (int u = 0; u < 8; ++u) {
      const float4 pp = p4s[j + u];
      a[0] = fmaf(pp.x, v[u], a[0]); a[1] = fmaf(pp.y, v[u], a[1]);
      a[2] = fmaf(pp.z, v[u], a[2]); a[3] = fmaf(pp.w, v[u], a[3]);
    }
  }
  for (; j < vl; ++j) {
    const float v = Vb[(size_t)j * DV_];
    const float4 pp = p4s[j];
    a[0] = fmaf(pp.x, v, a[0]); a[1] = fmaf(pp.y, v, a[1]);
    a[2] = fmaf(pp.z, v, a[2]); a[3] = fmaf(pp.w, v, a[3]);
  }
#pragma unroll
  for (int ii = 0; ii < 4; ++ii)
    out[(size_t)(b * LQ_ + i0 + ii) * DV_ + t] = a[ii];
}

extern "C" void kernel_launch(void* const* d_in, const int* in_sizes, int n_in,
                              void* d_out, int out_size, void* d_ws, size_t ws_size,
                              hipStream_t stream) {
  const float* queries    = (const float*)d_in[0];
  const float* keys       = (const float*)d_in[1];
  const float* values     = (const float*)d_in[2];
  const int*   valid_lens = (const int*)d_in[3];
  const float* Wq         = (const float*)d_in[4];
  const float* Wk         = (const float*)d_in[5];
  const float* wv         = (const float*)d_in[6];
  float* out = (float*)d_out;

  char* ws = (char*)d_ws;
  float* qp   = (float*)ws;                          // B*LQ*H  = 1 MB
  float* kpT  = (float*)(ws + (size_t)(1 << 20));    // B*H*LK  = 2 MB
  float* sc   = (float*)(ws + (size_t)(3 << 20));    // B*LQ*LK = 2 MB
  float* wsum = (float*)(ws + (size_t)(5 << 20));    // 4 B

  proj_kernel<<<(B_ * LQ_ + B_ * LK_) / 8, 256, 0, stream>>>(
      queries, keys, Wq, Wk, wv, valid_lens, qp, kpT, wsum);
  scores_kernel<<<B_ * (LQ_ / 2) * (LK_ / 256), 256, 0, stream>>>(
      qp, kpT, wv, wsum, valid_lens, sc);
  softmax_av_kernel<<<B_ * (LQ_ / 4), 512, 0, stream>>>(
      sc, values, valid_lens, out);
}